// Round 13
// baseline (169.133 us; speedup 1.0000x reference)
//
#include <hip/hip_runtime.h>

typedef __attribute__((ext_vector_type(8))) __bf16 bf16x8;
typedef __attribute__((ext_vector_type(4))) float f32x4;

#define DEVI static __device__ __forceinline__

DEVI unsigned short f2bf(float f) {
  unsigned int u = __float_as_uint(f);
  u += 0x7fffu + ((u >> 16) & 1u);
  return (unsigned short)(u >> 16);
}
DEVI float bf2f(unsigned short s) {
  return __uint_as_float(((unsigned int)s) << 16);
}

union Frag {
  bf16x8 v;
  __bf16 hf[8];
  unsigned short h[8];
  unsigned int w[4];
};

typedef __attribute__((address_space(1))) const void gv_t;
typedef __attribute__((address_space(3))) void sv_t;
#define GLOAD_LDS16(gp, lp) __builtin_amdgcn_global_load_lds((gv_t*)(gp), (sv_t*)(lp), 16, 0, 0)

// 0.125 * log2(e)
#define QSCALE 0.18033688011112042f

// ---------------------------------------------------------------------------
// Prep: fp32->bf16 conversion (x slice + 4 weights) AND iRPE bucket table.
// ---------------------------------------------------------------------------
__global__ __launch_bounds__(256) void k_prep(
    const float* __restrict__ x, const float* __restrict__ wq,
    const float* __restrict__ wk, const float* __restrict__ wv,
    const float* __restrict__ pw,
    unsigned short* __restrict__ xb, unsigned short* __restrict__ wb,
    unsigned char* __restrict__ bkt)
{
  int t = blockIdx.x * 256 + threadIdx.x;
  if (t >= 1572864) {  // bucket table
    int q = t - 1572864;               // 0..262143
    int i = q >> 9, j = q & 511;
    int ir = i / 23, ic = i - ir * 23;
    int jr = j / 23, jc = j - jr * 23;
    int dy = ir - jr, dx = ic - jc;
    double dis = rint(sqrt((double)(dy * dy + dx * dx)));
    int v;
    if (dis <= 1.9) {
      v = (int)rint(dis);
    } else {
      double far = rint(1.9 + log(dis / 1.9) * (1.9 / log(8.0)));
      v = (int)fmin(far, 3.8);
    }
    bkt[q] = (unsigned char)v;
    return;
  }
  const float* src;
  unsigned short* dst;
  if (t < 1048576) {
    long e0 = (long)t << 3;
    int m = (int)(e0 >> 10), cc = (int)(e0 & 1023);
    int b = m >> 9, i = m & 511;
    src = x + (((long)(b << 10) + i) << 10) + cc;
    dst = xb + ((long)m << 10) + cc;
  } else {
    long e0 = (long)(t - 1048576) << 3;
    int mat = (int)(e0 >> 20);
    long off = e0 & 1048575;
    const float* s = (mat == 0) ? wq : (mat == 1) ? wk : (mat == 2) ? wv : pw;
    src = s + off;
    dst = wb + e0;
  }
  float4 a = *(const float4*)src;
  float4 b4 = *(const float4*)(src + 4);
  uint4 o;
  o.x = f2bf(a.x)  | ((unsigned)f2bf(a.y)  << 16);
  o.y = f2bf(a.z)  | ((unsigned)f2bf(a.w)  << 16);
  o.z = f2bf(b4.x) | ((unsigned)f2bf(b4.y) << 16);
  o.w = f2bf(b4.z) | ((unsigned)f2bf(b4.w) << 16);
  *(uint4*)dst = o;
}

// ---------------------------------------------------------------------------
// QKV GEMM v13: 256x192 tile, BK=64, grid 512 (balanced 2 rounds), now with
// the m201-style 4-phase-per-K-tile schedule: each phase {ds_read quadrant +
// 2 stage ops -> barrier -> lgkmcnt(0) -> setprio(1) -> 12 MFMA -> setprio(0)
// -> barrier}. vmcnt only at kk/tile boundaries (counted, never 0 in-loop):
// issue order A00,A10|B0,B1|B2,A01|A11 -> vmcnt(4) end-ph1, vmcnt(2) end-ph3.
// ---------------------------------------------------------------------------
__global__ __launch_bounds__(512) void k_gemm8(
    const unsigned short* __restrict__ A,
    const unsigned short* __restrict__ Bw,
    unsigned short* __restrict__ qh, unsigned short* __restrict__ kh,
    unsigned short* __restrict__ vt)
{
  __shared__ unsigned short sL[2 * 28672];   // 114688 B

  const int bid = blockIdx.x;                 // 512 = 32 M x 16 N
  const int swz = (bid & 7) * 64 + (bid >> 3);   // bijective XCD swizzle
  const int tileN = swz & 15, tileM = swz >> 4;

  const int t = threadIdx.x;
  const int w = t >> 6, lane = t & 63;
  const int g4 = lane >> 4, c = lane & 15;
  const int wm = w >> 2, wn = w & 3;

  const char* lbase = (const char*)sL;
  const int acb = c * 64 + ((g4 * 16) ^ ((c & 8) ? 32 : 0));
  const int aoffbase = wm * 8192 + acb;
  int boff[3][2];
#pragma unroll
  for (int ni = 0; ni < 3; ++ni) {
    int row = wn * 48 + ni * 16 + c;
    int base = 32768 + (row >> 6) * 8192 + (row & 63) * 128;
    int rx = row & 7;
#pragma unroll
    for (int kk = 0; kk < 2; ++kk)
      boff[ni][kk] = base + (((kk * 4 + g4) ^ rx) << 4);
  }

  const int rowa = w * 16 + (lane >> 2);
  const int cola = ((lane & 3) * 8) ^ (((lane >> 2) & 8) ? 16 : 0);
  const unsigned short* sAp = A + (long)(tileM * 256 + rowa) * 1024 + cola;
  char* ldsta = (char*)sL + t * 16;
  const int rowbb = t >> 3;
  const int colbb = ((t & 7) ^ ((t >> 3) & 7)) * 8;
  const unsigned short* sBp = Bw + (long)(tileN * 192 + rowbb) * 1024 + colbb;
  char* ldstb = (char*)sL + 32768 + t * 16;

#define STGA(rh, kh, kn, ob) \
  GLOAD_LDS16(sAp + (long)(kn) * 64 + (rh) * 131072 + (kh) * 32, \
              ldsta + (ob) + (kh) * 16384 + (rh) * 8192)
#define STGB(gg, kn, ob) \
  GLOAD_LDS16(sBp + (long)(kn) * 64 + (gg) * 65536, \
              ldstb + (ob) + (gg) * 8192)

  f32x4 acc[8][3] = {};

  // prologue: tile 0 into buf0, issue order A00,A10,B0,B1,B2,A01,A11
  STGA(0, 0, 0, 0); STGA(1, 0, 0, 0);
  STGB(0, 0, 0); STGB(1, 0, 0); STGB(2, 0, 0);
  STGA(0, 1, 0, 0); STGA(1, 1, 0, 0);
  asm volatile("s_waitcnt vmcnt(2)" ::: "memory");
  __builtin_amdgcn_s_barrier();

#define MFMA12(base_, AREG, BREG)                                           \
  do {                                                                      \
    _Pragma("unroll")                                                       \
    for (int mi_ = 0; mi_ < 4; ++mi_)                                       \
      _Pragma("unroll")                                                     \
      for (int ni_ = 0; ni_ < 3; ++ni_)                                     \
        acc[(base_) + mi_][ni_] = __builtin_amdgcn_mfma_f32_16x16x32_bf16(  \
            AREG[mi_], BREG[ni_], acc[(base_) + mi_][ni_], 0, 0, 0);        \
  } while (0)

#pragma unroll 1
  for (int kt = 0; kt < 16; ++kt) {
    const int cb = (kt & 1) ? 57344 : 0;
    const int ob = cb ^ 57344;
    const int kn = (kt < 15) ? kt + 1 : 15;   // clamped junk re-stage at tail

    bf16x8 aa[4], bbf[3];
    // ---- ph0: kk0, acc[0..3] ----
#pragma unroll
    for (int q = 0; q < 4; ++q) aa[q] = *(const bf16x8*)(lbase + cb + aoffbase + q * 1024);
#pragma unroll
    for (int ni = 0; ni < 3; ++ni) bbf[ni] = *(const bf16x8*)(lbase + cb + boff[ni][0]);
    STGA(0, 0, kn, ob); STGA(1, 0, kn, ob);
    __builtin_amdgcn_s_barrier();
    asm volatile("s_waitcnt lgkmcnt(0)" ::: "memory");
    __builtin_amdgcn_s_setprio(1);
    MFMA12(0, aa, bbf);
    __builtin_amdgcn_s_setprio(0);
    __builtin_amdgcn_s_barrier();

    // ---- ph1: kk0, acc[4..7] ----
#pragma unroll
    for (int q = 0; q < 4; ++q) aa[q] = *(const bf16x8*)(lbase + cb + aoffbase + (4 + q) * 1024);
    STGB(0, kn, ob); STGB(1, kn, ob);
    __builtin_amdgcn_s_barrier();
    asm volatile("s_waitcnt lgkmcnt(0)" ::: "memory");
    __builtin_amdgcn_s_setprio(1);
    MFMA12(4, aa, bbf);
    __builtin_amdgcn_s_setprio(0);
    asm volatile("s_waitcnt vmcnt(4)" ::: "memory");   // A01,A11 of this tile landed
    __builtin_amdgcn_s_barrier();

    // ---- ph2: kk1, acc[0..3] ----
#pragma unroll
    for (int q = 0; q < 4; ++q) aa[q] = *(const bf16x8*)(lbase + cb + 16384 + aoffbase + q * 1024);
#pragma unroll
    for (int ni = 0; ni < 3; ++ni) bbf[ni] = *(const bf16x8*)(lbase + cb + boff[ni][1]);
    STGB(2, kn, ob); STGA(0, 1, kn, ob);
    __builtin_amdgcn_s_barrier();
    asm volatile("s_waitcnt lgkmcnt(0)" ::: "memory");
    __builtin_amdgcn_s_setprio(1);
    MFMA12(0, aa, bbf);
    __builtin_amdgcn_s_setprio(0);
    __builtin_amdgcn_s_barrier();

    // ---- ph3: kk1, acc[4..7] ----
#pragma unroll
    for (int q = 0; q < 4; ++q) aa[q] = *(const bf16x8*)(lbase + cb + 16384 + aoffbase + (4 + q) * 1024);
    STGA(1, 1, kn, ob);
    __builtin_amdgcn_s_barrier();
    asm volatile("s_waitcnt lgkmcnt(0)" ::: "memory");
    __builtin_amdgcn_s_setprio(1);
    MFMA12(4, aa, bbf);
    __builtin_amdgcn_s_setprio(0);
    asm volatile("s_waitcnt vmcnt(2)" ::: "memory");   // next tile's kk0 set landed
    __builtin_amdgcn_s_barrier();
  }
  asm volatile("s_waitcnt vmcnt(0)" ::: "memory");   // drain tail junk stages
#undef MFMA12
#undef STGA
#undef STGB

  const int m0 = tileM * 256 + wm * 128;
  const int n0 = tileN * 192 + wn * 48;
#pragma unroll
  for (int mi = 0; mi < 8; ++mi) {
    int mrow = m0 + mi * 16 + g4 * 4;
    int b = mrow >> 9, i = mrow & 511;
#pragma unroll
    for (int ni = 0; ni < 3; ++ni) {
      int n = n0 + ni * 16 + c;
      int mat = n >> 10;
      int cc = n & 1023;
      int h = cc >> 6, d = cc & 63;
      long bh = (long)(b * 16 + h);
      if (mat == 2) {
        unsigned int w0 = f2bf(acc[mi][ni][0]) | ((unsigned)f2bf(acc[mi][ni][1]) << 16);
        unsigned int w1 = f2bf(acc[mi][ni][2]) | ((unsigned)f2bf(acc[mi][ni][3]) << 16);
        *(uint2*)(vt + (bh * 64 + d) * 512 + i) = make_uint2(w0, w1);
      } else {
        float sc = (mat == 0) ? QSCALE : 1.0f;   // prescale Q for exp2 softmax
        unsigned short* dst = (mat == 0 ? qh : kh) + (bh * 512 + i) * 64 + d;
#pragma unroll
        for (int r = 0; r < 4; ++r)
          dst[(long)r * 64] = f2bf(acc[mi][ni][r] * sc);
      }
    }
  }
}

// ---------------------------------------------------------------------------
// Proj GEMM (ring-3, proven): BM=256, BN=128, BK=32, 512 thr, fp32 out + bias.
// ---------------------------------------------------------------------------
__global__ __launch_bounds__(512) void k_gemm_proj(
    const unsigned short* __restrict__ A,
    const unsigned short* __restrict__ Bw,
    float* __restrict__ out, const float* __restrict__ bias)
{
  __shared__ unsigned short sL[3 * 12288];   // 73728 B

  const int bid = blockIdx.x;
  const int swz = (bid & 7) * 32 + (bid >> 3);     // 256 blocks
  const int tileN = swz % 8, tileM = swz / 8;

  const int tid = threadIdx.x;
  const int w = tid >> 6, lane = tid & 63;
  const int g = lane >> 4, c = lane & 15;
  const int wm = w >> 1, wn = w & 1;

  const int sk = (g * 8) ^ ((c & 8) ? 16 : 0);
  int offA[4], offB[4];
#pragma unroll
  for (int i = 0; i < 4; ++i) {
    offA[i] = (wm * 4 + i) * 512 + c * 32 + sk;
    offB[i] = 8192 + (wn * 4 + i) * 512 + c * 32 + sk;
  }

  const int colb = ((lane & 3) * 8) ^ ((lane >= 32) ? 16 : 0);
  const unsigned short* gA0 = A  + ((long)(tileM * 256 + w * 32 + (lane >> 2))) * 1024 + colb;
  const unsigned short* gA1 = gA0 + 16 * 1024;
  const unsigned short* gB0 = Bw + ((long)(tileN * 128 + w * 16 + (lane >> 2))) * 1024 + colb;

#define STAGE(ktile, buf) do {                                             \
    const long ko_ = (long)(ktile) * 32;                                   \
    char* base_ = (char*)sL + (buf) * 24576;                               \
    GLOAD_LDS16(gA0 + ko_, base_ + (w * 2) * 1024 + lane * 16);            \
    GLOAD_LDS16(gA1 + ko_, base_ + (w * 2 + 1) * 1024 + lane * 16);        \
    GLOAD_LDS16(gB0 + ko_, base_ + 16384 + w * 1024 + lane * 16);          \
  } while (0)

  f32x4 acc[4][4] = {};

  STAGE(0, 0);
  STAGE(1, 1);

  int rb = 0, wbuf = 2;
  for (int t = 0; t < 32; ++t) {
    asm volatile("s_waitcnt vmcnt(3)" ::: "memory");
    __builtin_amdgcn_s_barrier();
    int kt = t + 2; if (kt > 31) kt = 31;
    STAGE(kt, wbuf);

    const unsigned short* lb = sL + rb * 12288;
    bf16x8 af[4], bf[4];
#pragma unroll
    for (int i = 0; i < 4; ++i) af[i] = *(const bf16x8*)(lb + offA[i]);
#pragma unroll
    for (int i = 0; i < 4; ++i) bf[i] = *(const bf16x8*)(lb + offB[i]);

    __builtin_amdgcn_s_setprio(1);
#pragma unroll
    for (int mi = 0; mi < 4; ++mi)
#pragma unroll
      for (int ni = 0; ni < 4; ++ni)
        acc[mi][ni] = __builtin_amdgcn_mfma_f32_16x16x32_bf16(af[mi], bf[ni], acc[mi][ni], 0, 0, 0);
    __builtin_amdgcn_s_setprio(0);
    asm volatile("s_waitcnt lgkmcnt(0)" ::: "memory");

    rb = (rb == 2) ? 0 : rb + 1;
    wbuf = (wbuf == 2) ? 0 : wbuf + 1;
  }
  asm volatile("s_waitcnt vmcnt(0)" ::: "memory");
#undef STAGE

  const int m0 = tileM * 256 + wm * 64;
  const int n0 = tileN * 128 + wn * 64;
#pragma unroll
  for (int mi = 0; mi < 4; ++mi) {
    int mrow = m0 + mi * 16 + g * 4;
#pragma unroll
    for (int ni = 0; ni < 4; ++ni) {
      int n = n0 + ni * 16 + c;
      float bv = bias[n];
#pragma unroll
      for (int r = 0; r < 4; ++r)
        out[(long)(mrow + r) * 1024 + n] = acc[mi][ni][r] + bv;
    }
  }
}

// ---------------------------------------------------------------------------
// Fused attention v13: R12's staged structure + 2-way KV split.
// 512 blocks (head x kvh) x 512 thr; each wave 64 q-rows x 8 KV tiles.
// PLAIN launch_bounds(512): natural VGPR (~100-110) -> with LDS 42.8KB,
// 2 blocks/CU co-resident -> 4 waves/SIMD (R11's forced (512,4) cap caused
// the spill; this relies on natural allocation). Unnormalized additive
// partials (no-max exp2 softmax) -> po0/po1 + row sums; k_merge combines.
// ---------------------------------------------------------------------------
__global__ __launch_bounds__(512) void k_attn(
    const unsigned short* __restrict__ qh, const unsigned short* __restrict__ kh,
    const unsigned short* __restrict__ vt, const float* __restrict__ rpe,
    const unsigned char* __restrict__ bkt,
    unsigned short* __restrict__ po0, unsigned short* __restrict__ po1,
    float* __restrict__ ls0, float* __restrict__ ls1)
{
  __shared__ char ring[3 * 8192];      // slot: K[32][64] @0, V[64][32] @4096
  __shared__ float lt_lds[512 * 9];
  const int bid = blockIdx.x;
  const int head = bid >> 1, kvh = bid & 1;
  const int b = head >> 4, h = head & 15;
  const int t = threadIdx.x;
  const int w = t >> 6, lane = t & 63;
  const int g = lane >> 4, c = lane & 15;
  const int qbase = w * 64;
  const int tb0 = kvh * 8;             // this block's 8 KV tiles: tb0..tb0+7
  const unsigned short* Q = qh + (long)head * 512 * 64;
  const unsigned short* K = kh + (long)head * 512 * 64;
  const unsigned short* V = vt + (long)head * 64 * 512;
  unsigned short* po = kvh ? po1 : po0;
  float* lsp = kvh ? ls1 : ls0;

  // --- stage source pointers (pre-swizzled), same as R12 ---
  const unsigned short* sgp;
  char* sld;
  int sjstep;
  if (t < 256) {
    int row = t >> 3;
    int chunk = (t & 7) ^ (row & 7);
    sgp = K + (long)row * 64 + chunk * 8;
    sld = ring + t * 16;
    sjstep = 64;
  } else {
    int u = t - 256;
    int row = u >> 2;
    int chunk = (u & 3) ^ (row & 3);
    sgp = V + (long)row * 512 + chunk * 8;
    sld = ring + 4096 + u * 16;
    sjstep = 1;
  }

#define STAGE(jt_, slot_) \
  GLOAD_LDS16(sgp + (long)(jt_) * 32 * sjstep, sld + (slot_) * 8192)

  Frag qu[4][2];
#pragma unroll
  for (int it = 0; it < 4; ++it)
#pragma unroll
    for (int kk = 0; kk < 2; ++kk)
      qu[it][kk].v = *(const bf16x8*)(Q + (qbase + it * 16 + c) * 64 + kk * 32 + g * 8);

  STAGE(tb0 + 0, 0);
  STAGE(tb0 + 1, 1);

  float lt[4][7] = {};
#pragma unroll
  for (int kk = 0; kk < 2; ++kk)
#pragma unroll
    for (int tt = 0; tt < 8; ++tt) {
      int d = kk * 32 + g * 8 + tt;
      const float* rr = rpe + d * 7;
      float r0 = rr[0], r1 = rr[1], r2 = rr[2], r3 = rr[3], r4 = rr[4], r5 = rr[5], r6 = rr[6];
#pragma unroll
      for (int it = 0; it < 4; ++it) {
        float qv = bf2f(qu[it][kk].h[tt]);
        lt[it][0] += qv * r0; lt[it][1] += qv * r1; lt[it][2] += qv * r2;
        lt[it][3] += qv * r3; lt[it][4] += qv * r4; lt[it][5] += qv * r5;
        lt[it][6] += qv * r6;
      }
    }
#pragma unroll
  for (int it = 0; it < 4; ++it)
#pragma unroll
    for (int n = 0; n < 7; ++n) {
      float v = lt[it][n];
      v += __shfl_xor(v, 16);
      v += __shfl_xor(v, 32);
      if (g == 0) lt_lds[(qbase + it * 16 + c) * 9 + n] = v * 8.0f;
    }
  // wave-local write->read: no barrier needed

  int rowb36[4];
  const unsigned char* bktp[4];
#pragma unroll
  for (int it = 0; it < 4; ++it) {
    int row = qbase + it * 16 + c;
    rowb36[it] = row * 36;
    bktp[it] = bkt + (long)row * 512 + g * 8;
  }

  const int jperm = (c >> 2) * 8 + (c & 3);
  int koff[2][2];
#pragma unroll
  for (int jt = 0; jt < 2; ++jt) {
    int jp = jperm + jt * 4;
#pragma unroll
    for (int kk = 0; kk < 2; ++kk)
      koff[jt][kk] = jp * 128 + (((kk * 4 + g) ^ (jp & 7)) << 4);
  }
  int voff[4];
#pragma unroll
  for (int dt = 0; dt < 4; ++dt) {
    int r = dt * 16 + c;
    voff[dt] = 4096 + r * 64 + ((g ^ (r & 3)) << 4);
  }

  f32x4 oacc[4][4] = {};
  float lp[4] = {0.f, 0.f, 0.f, 0.f};

  int rb = 0, wbuf = 2;
#pragma unroll 1
  for (int kt = 0; kt < 8; ++kt) {
    asm volatile("s_waitcnt vmcnt(1)" ::: "memory");
    __builtin_amdgcn_s_barrier();
    int kn = tb0 + ((kt < 6) ? kt + 2 : 7);   // clamped junk re-stage at tail
    STAGE(kn, wbuf);

    const char* lb = ring + rb * 8192;
    const int jb = (tb0 + kt) * 32;

    Frag kf[2][2];
#pragma unroll
    for (int jt = 0; jt < 2; ++jt)
#pragma unroll
      for (int kk = 0; kk < 2; ++kk)
        kf[jt][kk].v = *(const bf16x8*)(lb + koff[jt][kk]);

    uint2 bb[4];
#pragma unroll
    for (int it = 0; it < 4; ++it)
      bb[it] = *(const uint2*)(bktp[it] + jb);

    f32x4 s[2][4];
#pragma unroll
    for (int jt = 0; jt < 2; ++jt)
#pragma unroll
      for (int it = 0; it < 4; ++it) {
        f32x4 z = {0.f, 0.f, 0.f, 0.f};
        z = __builtin_amdgcn_mfma_f32_16x16x32_bf16(kf[jt][0].v, qu[it][0].v, z, 0, 0, 0);
        s[jt][it] = __builtin_amdgcn_mfma_f32_16x16x32_bf16(kf[jt][1].v, qu[it][1].v, z, 0, 0, 0);
      }

    Frag pfr[4];
#pragma unroll
    for (int it = 0; it < 4; ++it) {
      float ps = 0.f;
#pragma unroll
      for (int jt = 0; jt < 2; ++jt) {
        unsigned int bw = jt ? bb[it].y : bb[it].x;
#pragma unroll
        for (int r = 0; r < 4; ++r) {
          int bno = (bw >> (8 * r)) & 255;
          float bias = *(const float*)((const char*)lt_lds + rowb36[it] + (bno << 2));
          float sv = s[jt][it][r] + bias;
          float p;
          asm("v_exp_f32 %0, %1" : "=v"(p) : "v"(sv));
          ps += p;
          pfr[it].hf[jt * 4 + r] = (__bf16)p;
        }
      }
      lp[it] += ps;
    }

    bf16x8 vf[4];
#pragma unroll
    for (int dt = 0; dt < 4; ++dt)
      vf[dt] = *(const bf16x8*)(lb + voff[dt]);

#pragma unroll
    for (int dt = 0; dt < 4; ++dt)
#pragma unroll
      for (int it = 0; it < 4; ++it)
        oacc[dt][it] = __builtin_amdgcn_mfma_f32_16x16x32_bf16(vf[dt], pfr[it].v, oacc[dt][it], 0, 0, 0);

    asm volatile("s_waitcnt lgkmcnt(0)" ::: "memory");
    rb = (rb == 2) ? 0 : rb + 1;
    wbuf = (wbuf == 2) ? 0 : wbuf + 1;
  }
  asm volatile("s_waitcnt vmcnt(0)" ::: "memory");
#undef STAGE

  // per-row partial sums
#pragma unroll
  for (int it = 0; it < 4; ++it) {
    float v = lp[it];
    v += __shfl_xor(v, 16);
    v += __shfl_xor(v, 32);
    if (g == 0) lsp[head * 512 + qbase + it * 16 + c] = v;
  }

  // unnormalized partial O (bf16, additive)
#pragma unroll
  for (int dt = 0; dt < 4; ++dt)
#pragma unroll
    for (int it = 0; it < 4; ++it) {
      int irow = qbase + it * 16 + c;
      int d0 = dt * 16 + g * 4;
      unsigned int w0 = f2bf(oacc[dt][it][0]) | ((unsigned)f2bf(oacc[dt][it][1]) << 16);
      unsigned int w1 = f2bf(oacc[dt][it][2]) | ((unsigned)f2bf(oacc[dt][it][3]) << 16);
      *(uint2*)(po + ((long)(b * 512 + irow)) * 1024 + h * 64 + d0) = make_uint2(w0, w1);
    }
}

// ---------------------------------------------------------------------------
// Merge: ao = (po0 + po1) / (ls0 + ls1), in-place over po0. 8 elems/thread.
// ---------------------------------------------------------------------------
__global__ __launch_bounds__(256) void k_merge(
    const unsigned short* __restrict__ po1, const float* __restrict__ ls0,
    const float* __restrict__ ls1, unsigned short* __restrict__ ao)
{
  int idx = blockIdx.x * 256 + threadIdx.x;   // 0..1048575
  int m = idx >> 7;
  int n0 = (idx & 127) << 3;
  int head = (m >> 9) * 16 + (n0 >> 6);
  int i = m & 511;
  float li = 1.0f / (ls0[head * 512 + i] + ls1[head * 512 + i]);
  long off = (long)m * 1024 + n0;
  uint2 a = *(const uint2*)(ao + off);
  uint2 bq = *(const uint2*)(po1 + off);
  unsigned int r[2];
#pragma unroll
  for (int q = 0; q < 2; ++q) {
    unsigned int ua = q ? a.y : a.x, ub = q ? bq.y : bq.x;
    float f0 = (bf2f((unsigned short)(ua & 0xffff)) + bf2f((unsigned short)(ub & 0xffff))) * li;
    float f1 = (bf2f((unsigned short)(ua >> 16)) + bf2f((unsigned short)(ub >> 16))) * li;
    r[q] = f2bf(f0) | ((unsigned)f2bf(f1) << 16);
  }
  uint2 a2 = *(const uint2*)(ao + off + 4);
  uint2 b2 = *(const uint2*)(po1 + off + 4);
  unsigned int r2[2];
#pragma unroll
  for (int q = 0; q < 2; ++q) {
    unsigned int ua = q ? a2.y : a2.x, ub = q ? b2.y : b2.x;
    float f0 = (bf2f((unsigned short)(ua & 0xffff)) + bf2f((unsigned short)(ub & 0xffff))) * li;
    float f1 = (bf2f((unsigned short)(ua >> 16)) + bf2f((unsigned short)(ub >> 16))) * li;
    r2[q] = f2bf(f0) | ((unsigned)f2bf(f1) << 16);
  }
  *(uint4*)(ao + off) = make_uint4(r[0], r[1], r2[0], r2[1]);
}

// ---------------------------------------------------------------------------
extern "C" void kernel_launch(void* const* d_in, const int* in_sizes, int n_in,
                              void* d_out, int out_size, void* d_ws, size_t ws_size,
                              hipStream_t stream) {
  const float* x   = (const float*)d_in[0];
  const float* wq  = (const float*)d_in[1];
  const float* wk  = (const float*)d_in[2];
  const float* wv  = (const float*)d_in[3];
  const float* rpe = (const float*)d_in[4];
  const float* pw  = (const float*)d_in[5];
  const float* pb  = (const float*)d_in[6];
  float* out = (float*)d_out;

  char* ws = (char*)d_ws;
  unsigned short* xb  = (unsigned short*)(ws);                 // 8192x1024 bf16 (16 MB)
  unsigned short* wb  = (unsigned short*)(ws + 16777216);      // 4x1024x1024 bf16 (8 MB)
  unsigned short* qhp = (unsigned short*)(ws + 25165824);      // [bh][512][64]
  unsigned short* khp = (unsigned short*)(ws + 41943040);      // [bh][512][64]
  unsigned short* vtp = (unsigned short*)(ws + 58720256);      // [bh][64][512]
  unsigned char*  bkt = (unsigned char*)(ws + 75497472);       // 512x512
  unsigned short* po0 = xb;                                    // alias: xb dead after QKV gemm
  // partial 1 + row-sums live in d_out (33.5MB) until proj overwrites it:
  unsigned short* po1 = (unsigned short*)d_out;                // 16 MB bf16
  float* ls0 = (float*)((char*)d_out + 16777216);              // 512 KB
  float* ls1 = (float*)((char*)d_out + 17825792);              // 512 KB

  k_prep<<<dim3(7168), dim3(256), 0, stream>>>(x, wq, wk, wv, pw, xb, wb, bkt);
  k_gemm8<<<dim3(512), dim3(512), 0, stream>>>(xb, wb, qhp, khp, vtp);
  k_attn<<<dim3(512), dim3(512), 0, stream>>>(qhp, khp, vtp, rpe, bkt, po0, po1, ls0, ls1);
  k_merge<<<dim3(4096), dim3(256), 0, stream>>>(po1, ls0, ls1, po0);
  k_gemm_proj<<<dim3(256), dim3(512), 0, stream>>>(po0, wb + 3 * 1048576, out, pb);
}

// Round 14
// 148.413 us; speedup vs baseline: 1.1396x; 1.1396x over previous
//
#include <hip/hip_runtime.h>

typedef __attribute__((ext_vector_type(8))) __bf16 bf16x8;
typedef __attribute__((ext_vector_type(4))) float f32x4;

#define DEVI static __device__ __forceinline__

DEVI unsigned short f2bf(float f) {
  unsigned int u = __float_as_uint(f);
  u += 0x7fffu + ((u >> 16) & 1u);
  return (unsigned short)(u >> 16);
}
DEVI float bf2f(unsigned short s) {
  return __uint_as_float(((unsigned int)s) << 16);
}

union Frag {
  bf16x8 v;
  __bf16 hf[8];
  unsigned short h[8];
  unsigned int w[4];
};

typedef __attribute__((address_space(1))) const void gv_t;
typedef __attribute__((address_space(3))) void sv_t;
#define GLOAD_LDS16(gp, lp) __builtin_amdgcn_global_load_lds((gv_t*)(gp), (sv_t*)(lp), 16, 0, 0)

// 0.125 * log2(e)
#define QSCALE 0.18033688011112042f

// ---------------------------------------------------------------------------
// Prep: fp32->bf16 conversion (x slice + 4 weights) AND iRPE bucket table.
// ---------------------------------------------------------------------------
__global__ __launch_bounds__(256) void k_prep(
    const float* __restrict__ x, const float* __restrict__ wq,
    const float* __restrict__ wk, const float* __restrict__ wv,
    const float* __restrict__ pw,
    unsigned short* __restrict__ xb, unsigned short* __restrict__ wb,
    unsigned char* __restrict__ bkt)
{
  int t = blockIdx.x * 256 + threadIdx.x;
  if (t >= 1572864) {  // bucket table
    int q = t - 1572864;               // 0..262143
    int i = q >> 9, j = q & 511;
    int ir = i / 23, ic = i - ir * 23;
    int jr = j / 23, jc = j - jr * 23;
    int dy = ir - jr, dx = ic - jc;
    double dis = rint(sqrt((double)(dy * dy + dx * dx)));
    int v;
    if (dis <= 1.9) {
      v = (int)rint(dis);
    } else {
      double far = rint(1.9 + log(dis / 1.9) * (1.9 / log(8.0)));
      v = (int)fmin(far, 3.8);
    }
    bkt[q] = (unsigned char)v;
    return;
  }
  const float* src;
  unsigned short* dst;
  if (t < 1048576) {
    long e0 = (long)t << 3;
    int m = (int)(e0 >> 10), cc = (int)(e0 & 1023);
    int b = m >> 9, i = m & 511;
    src = x + (((long)(b << 10) + i) << 10) + cc;
    dst = xb + ((long)m << 10) + cc;
  } else {
    long e0 = (long)(t - 1048576) << 3;
    int mat = (int)(e0 >> 20);
    long off = e0 & 1048575;
    const float* s = (mat == 0) ? wq : (mat == 1) ? wk : (mat == 2) ? wv : pw;
    src = s + off;
    dst = wb + e0;
  }
  float4 a = *(const float4*)src;
  float4 b4 = *(const float4*)(src + 4);
  uint4 o;
  o.x = f2bf(a.x)  | ((unsigned)f2bf(a.y)  << 16);
  o.y = f2bf(a.z)  | ((unsigned)f2bf(a.w)  << 16);
  o.z = f2bf(b4.x) | ((unsigned)f2bf(b4.y) << 16);
  o.w = f2bf(b4.z) | ((unsigned)f2bf(b4.w) << 16);
  *(uint4*)dst = o;
}

// ---------------------------------------------------------------------------
// QKV GEMM (R13 4-phase): 256x192 tile, BK=64, grid 512 (balanced 2 rounds),
// m201-style 4-phase-per-K-tile schedule: each phase {ds_read quadrant +
// 2 stage ops -> barrier -> lgkmcnt(0) -> setprio(1) -> 12 MFMA -> setprio(0)
// -> barrier}. vmcnt only at kk/tile boundaries (counted, never 0 in-loop).
// ---------------------------------------------------------------------------
__global__ __launch_bounds__(512) void k_gemm8(
    const unsigned short* __restrict__ A,
    const unsigned short* __restrict__ Bw,
    unsigned short* __restrict__ qh, unsigned short* __restrict__ kh,
    unsigned short* __restrict__ vt)
{
  __shared__ unsigned short sL[2 * 28672];   // 114688 B

  const int bid = blockIdx.x;                 // 512 = 32 M x 16 N
  const int swz = (bid & 7) * 64 + (bid >> 3);   // bijective XCD swizzle
  const int tileN = swz & 15, tileM = swz >> 4;

  const int t = threadIdx.x;
  const int w = t >> 6, lane = t & 63;
  const int g4 = lane >> 4, c = lane & 15;
  const int wm = w >> 2, wn = w & 3;

  const char* lbase = (const char*)sL;
  const int acb = c * 64 + ((g4 * 16) ^ ((c & 8) ? 32 : 0));
  const int aoffbase = wm * 8192 + acb;
  int boff[3][2];
#pragma unroll
  for (int ni = 0; ni < 3; ++ni) {
    int row = wn * 48 + ni * 16 + c;
    int base = 32768 + (row >> 6) * 8192 + (row & 63) * 128;
    int rx = row & 7;
#pragma unroll
    for (int kk = 0; kk < 2; ++kk)
      boff[ni][kk] = base + (((kk * 4 + g4) ^ rx) << 4);
  }

  const int rowa = w * 16 + (lane >> 2);
  const int cola = ((lane & 3) * 8) ^ (((lane >> 2) & 8) ? 16 : 0);
  const unsigned short* sAp = A + (long)(tileM * 256 + rowa) * 1024 + cola;
  char* ldsta = (char*)sL + t * 16;
  const int rowbb = t >> 3;
  const int colbb = ((t & 7) ^ ((t >> 3) & 7)) * 8;
  const unsigned short* sBp = Bw + (long)(tileN * 192 + rowbb) * 1024 + colbb;
  char* ldstb = (char*)sL + 32768 + t * 16;

#define STGA(rh, kh, kn, ob) \
  GLOAD_LDS16(sAp + (long)(kn) * 64 + (rh) * 131072 + (kh) * 32, \
              ldsta + (ob) + (kh) * 16384 + (rh) * 8192)
#define STGB(gg, kn, ob) \
  GLOAD_LDS16(sBp + (long)(kn) * 64 + (gg) * 65536, \
              ldstb + (ob) + (gg) * 8192)

  f32x4 acc[8][3] = {};

  // prologue: tile 0 into buf0, issue order A00,A10,B0,B1,B2,A01,A11
  STGA(0, 0, 0, 0); STGA(1, 0, 0, 0);
  STGB(0, 0, 0); STGB(1, 0, 0); STGB(2, 0, 0);
  STGA(0, 1, 0, 0); STGA(1, 1, 0, 0);
  asm volatile("s_waitcnt vmcnt(2)" ::: "memory");
  __builtin_amdgcn_s_barrier();

#define MFMA12(base_, AREG, BREG)                                           \
  do {                                                                      \
    _Pragma("unroll")                                                       \
    for (int mi_ = 0; mi_ < 4; ++mi_)                                       \
      _Pragma("unroll")                                                     \
      for (int ni_ = 0; ni_ < 3; ++ni_)                                     \
        acc[(base_) + mi_][ni_] = __builtin_amdgcn_mfma_f32_16x16x32_bf16(  \
            AREG[mi_], BREG[ni_], acc[(base_) + mi_][ni_], 0, 0, 0);        \
  } while (0)

#pragma unroll 1
  for (int kt = 0; kt < 16; ++kt) {
    const int cb = (kt & 1) ? 57344 : 0;
    const int ob = cb ^ 57344;
    const int kn = (kt < 15) ? kt + 1 : 15;   // clamped junk re-stage at tail

    bf16x8 aa[4], bbf[3];
    // ---- ph0: kk0, acc[0..3] ----
#pragma unroll
    for (int q = 0; q < 4; ++q) aa[q] = *(const bf16x8*)(lbase + cb + aoffbase + q * 1024);
#pragma unroll
    for (int ni = 0; ni < 3; ++ni) bbf[ni] = *(const bf16x8*)(lbase + cb + boff[ni][0]);
    STGA(0, 0, kn, ob); STGA(1, 0, kn, ob);
    __builtin_amdgcn_s_barrier();
    asm volatile("s_waitcnt lgkmcnt(0)" ::: "memory");
    __builtin_amdgcn_s_setprio(1);
    MFMA12(0, aa, bbf);
    __builtin_amdgcn_s_setprio(0);
    __builtin_amdgcn_s_barrier();

    // ---- ph1: kk0, acc[4..7] ----
#pragma unroll
    for (int q = 0; q < 4; ++q) aa[q] = *(const bf16x8*)(lbase + cb + aoffbase + (4 + q) * 1024);
    STGB(0, kn, ob); STGB(1, kn, ob);
    __builtin_amdgcn_s_barrier();
    asm volatile("s_waitcnt lgkmcnt(0)" ::: "memory");
    __builtin_amdgcn_s_setprio(1);
    MFMA12(4, aa, bbf);
    __builtin_amdgcn_s_setprio(0);
    asm volatile("s_waitcnt vmcnt(4)" ::: "memory");   // A01,A11 of this tile landed
    __builtin_amdgcn_s_barrier();

    // ---- ph2: kk1, acc[0..3] ----
#pragma unroll
    for (int q = 0; q < 4; ++q) aa[q] = *(const bf16x8*)(lbase + cb + 16384 + aoffbase + q * 1024);
#pragma unroll
    for (int ni = 0; ni < 3; ++ni) bbf[ni] = *(const bf16x8*)(lbase + cb + boff[ni][1]);
    STGB(2, kn, ob); STGA(0, 1, kn, ob);
    __builtin_amdgcn_s_barrier();
    asm volatile("s_waitcnt lgkmcnt(0)" ::: "memory");
    __builtin_amdgcn_s_setprio(1);
    MFMA12(0, aa, bbf);
    __builtin_amdgcn_s_setprio(0);
    __builtin_amdgcn_s_barrier();

    // ---- ph3: kk1, acc[4..7] ----
#pragma unroll
    for (int q = 0; q < 4; ++q) aa[q] = *(const bf16x8*)(lbase + cb + 16384 + aoffbase + (4 + q) * 1024);
    STGA(1, 1, kn, ob);
    __builtin_amdgcn_s_barrier();
    asm volatile("s_waitcnt lgkmcnt(0)" ::: "memory");
    __builtin_amdgcn_s_setprio(1);
    MFMA12(4, aa, bbf);
    __builtin_amdgcn_s_setprio(0);
    asm volatile("s_waitcnt vmcnt(2)" ::: "memory");   // next tile's kk0 set landed
    __builtin_amdgcn_s_barrier();
  }
  asm volatile("s_waitcnt vmcnt(0)" ::: "memory");   // drain tail junk stages
#undef MFMA12
#undef STGA
#undef STGB

  const int m0 = tileM * 256 + wm * 128;
  const int n0 = tileN * 192 + wn * 48;
#pragma unroll
  for (int mi = 0; mi < 8; ++mi) {
    int mrow = m0 + mi * 16 + g4 * 4;
    int b = mrow >> 9, i = mrow & 511;
#pragma unroll
    for (int ni = 0; ni < 3; ++ni) {
      int n = n0 + ni * 16 + c;
      int mat = n >> 10;
      int cc = n & 1023;
      int h = cc >> 6, d = cc & 63;
      long bh = (long)(b * 16 + h);
      if (mat == 2) {
        unsigned int w0 = f2bf(acc[mi][ni][0]) | ((unsigned)f2bf(acc[mi][ni][1]) << 16);
        unsigned int w1 = f2bf(acc[mi][ni][2]) | ((unsigned)f2bf(acc[mi][ni][3]) << 16);
        *(uint2*)(vt + (bh * 64 + d) * 512 + i) = make_uint2(w0, w1);
      } else {
        float sc = (mat == 0) ? QSCALE : 1.0f;   // prescale Q for exp2 softmax
        unsigned short* dst = (mat == 0 ? qh : kh) + (bh * 512 + i) * 64 + d;
#pragma unroll
        for (int r = 0; r < 4; ++r)
          dst[(long)r * 64] = f2bf(acc[mi][ni][r] * sc);
      }
    }
  }
}

// ---------------------------------------------------------------------------
// Proj GEMM (ring-3, proven): BM=256, BN=128, BK=32, 512 thr, fp32 out + bias.
// ---------------------------------------------------------------------------
__global__ __launch_bounds__(512) void k_gemm_proj(
    const unsigned short* __restrict__ A,
    const unsigned short* __restrict__ Bw,
    float* __restrict__ out, const float* __restrict__ bias)
{
  __shared__ unsigned short sL[3 * 12288];   // 73728 B

  const int bid = blockIdx.x;
  const int swz = (bid & 7) * 32 + (bid >> 3);     // 256 blocks
  const int tileN = swz % 8, tileM = swz / 8;

  const int tid = threadIdx.x;
  const int w = tid >> 6, lane = tid & 63;
  const int g = lane >> 4, c = lane & 15;
  const int wm = w >> 1, wn = w & 1;

  const int sk = (g * 8) ^ ((c & 8) ? 16 : 0);
  int offA[4], offB[4];
#pragma unroll
  for (int i = 0; i < 4; ++i) {
    offA[i] = (wm * 4 + i) * 512 + c * 32 + sk;
    offB[i] = 8192 + (wn * 4 + i) * 512 + c * 32 + sk;
  }

  const int colb = ((lane & 3) * 8) ^ ((lane >= 32) ? 16 : 0);
  const unsigned short* gA0 = A  + ((long)(tileM * 256 + w * 32 + (lane >> 2))) * 1024 + colb;
  const unsigned short* gA1 = gA0 + 16 * 1024;
  const unsigned short* gB0 = Bw + ((long)(tileN * 128 + w * 16 + (lane >> 2))) * 1024 + colb;

#define STAGE(ktile, buf) do {                                             \
    const long ko_ = (long)(ktile) * 32;                                   \
    char* base_ = (char*)sL + (buf) * 24576;                               \
    GLOAD_LDS16(gA0 + ko_, base_ + (w * 2) * 1024 + lane * 16);            \
    GLOAD_LDS16(gA1 + ko_, base_ + (w * 2 + 1) * 1024 + lane * 16);        \
    GLOAD_LDS16(gB0 + ko_, base_ + 16384 + w * 1024 + lane * 16);          \
  } while (0)

  f32x4 acc[4][4] = {};

  STAGE(0, 0);
  STAGE(1, 1);

  int rb = 0, wbuf = 2;
  for (int t = 0; t < 32; ++t) {
    asm volatile("s_waitcnt vmcnt(3)" ::: "memory");
    __builtin_amdgcn_s_barrier();
    int kt = t + 2; if (kt > 31) kt = 31;
    STAGE(kt, wbuf);

    const unsigned short* lb = sL + rb * 12288;
    bf16x8 af[4], bf[4];
#pragma unroll
    for (int i = 0; i < 4; ++i) af[i] = *(const bf16x8*)(lb + offA[i]);
#pragma unroll
    for (int i = 0; i < 4; ++i) bf[i] = *(const bf16x8*)(lb + offB[i]);

    __builtin_amdgcn_s_setprio(1);
#pragma unroll
    for (int mi = 0; mi < 4; ++mi)
#pragma unroll
      for (int ni = 0; ni < 4; ++ni)
        acc[mi][ni] = __builtin_amdgcn_mfma_f32_16x16x32_bf16(af[mi], bf[ni], acc[mi][ni], 0, 0, 0);
    __builtin_amdgcn_s_setprio(0);
    asm volatile("s_waitcnt lgkmcnt(0)" ::: "memory");

    rb = (rb == 2) ? 0 : rb + 1;
    wbuf = (wbuf == 2) ? 0 : wbuf + 1;
  }
  asm volatile("s_waitcnt vmcnt(0)" ::: "memory");
#undef STAGE

  const int m0 = tileM * 256 + wm * 64;
  const int n0 = tileN * 128 + wn * 64;
#pragma unroll
  for (int mi = 0; mi < 4; ++mi) {
    int mrow = m0 + mi * 16 + g * 4;
#pragma unroll
    for (int ni = 0; ni < 4; ++ni) {
      int n = n0 + ni * 16 + c;
      float bv = bias[n];
#pragma unroll
      for (int r = 0; r < 4; ++r)
        out[(long)(mrow + r) * 1024 + n] = acc[mi][ni][r] + bv;
    }
  }
}

// ---------------------------------------------------------------------------
// Fused attention (R12, best): 256 blocks x 512 thr, it=4, exp2 no-max
// softmax, ring-3 global_load_lds K/V staging. Unified-reg note: 104 arch +
// 64 acc = 168 -> 2 waves/SIMD is a hard cap at it=4; do NOT force more.
// ---------------------------------------------------------------------------
__global__ __launch_bounds__(512) void k_attn(
    const unsigned short* __restrict__ qh, const unsigned short* __restrict__ kh,
    const unsigned short* __restrict__ vt, const float* __restrict__ rpe,
    const unsigned char* __restrict__ bkt, unsigned short* __restrict__ ao)
{
  __shared__ char ring[3 * 8192];      // slot: K[32][64] @0, V[64][32] @4096
  __shared__ float lt_lds[512 * 9];
  const int head = blockIdx.x;
  const int b = head >> 4, h = head & 15;
  const int t = threadIdx.x;
  const int w = t >> 6, lane = t & 63;
  const int g = lane >> 4, c = lane & 15;
  const int qbase = w * 64;
  const unsigned short* Q = qh + (long)head * 512 * 64;
  const unsigned short* K = kh + (long)head * 512 * 64;
  const unsigned short* V = vt + (long)head * 64 * 512;

  const unsigned short* sgp;
  char* sld;
  int sjstep;
  if (t < 256) {
    int row = t >> 3;
    int chunk = (t & 7) ^ (row & 7);
    sgp = K + (long)row * 64 + chunk * 8;
    sld = ring + t * 16;
    sjstep = 64;
  } else {
    int u = t - 256;
    int row = u >> 2;
    int chunk = (u & 3) ^ (row & 3);
    sgp = V + (long)row * 512 + chunk * 8;
    sld = ring + 4096 + u * 16;
    sjstep = 1;
  }

#define STAGE(jt_, slot_) \
  GLOAD_LDS16(sgp + (long)(jt_) * 32 * sjstep, sld + (slot_) * 8192)

  Frag qu[4][2];
#pragma unroll
  for (int it = 0; it < 4; ++it)
#pragma unroll
    for (int kk = 0; kk < 2; ++kk)
      qu[it][kk].v = *(const bf16x8*)(Q + (qbase + it * 16 + c) * 64 + kk * 32 + g * 8);

  STAGE(0, 0);
  STAGE(1, 1);

  float lt[4][7] = {};
#pragma unroll
  for (int kk = 0; kk < 2; ++kk)
#pragma unroll
    for (int tt = 0; tt < 8; ++tt) {
      int d = kk * 32 + g * 8 + tt;
      const float* rr = rpe + d * 7;
      float r0 = rr[0], r1 = rr[1], r2 = rr[2], r3 = rr[3], r4 = rr[4], r5 = rr[5], r6 = rr[6];
#pragma unroll
      for (int it = 0; it < 4; ++it) {
        float qv = bf2f(qu[it][kk].h[tt]);
        lt[it][0] += qv * r0; lt[it][1] += qv * r1; lt[it][2] += qv * r2;
        lt[it][3] += qv * r3; lt[it][4] += qv * r4; lt[it][5] += qv * r5;
        lt[it][6] += qv * r6;
      }
    }
#pragma unroll
  for (int it = 0; it < 4; ++it)
#pragma unroll
    for (int n = 0; n < 7; ++n) {
      float v = lt[it][n];
      v += __shfl_xor(v, 16);
      v += __shfl_xor(v, 32);
      if (g == 0) lt_lds[(qbase + it * 16 + c) * 9 + n] = v * 8.0f;
    }
  // wave-local write->read: no barrier needed

  int rowb36[4];
  const unsigned char* bktp[4];
#pragma unroll
  for (int it = 0; it < 4; ++it) {
    int row = qbase + it * 16 + c;
    rowb36[it] = row * 36;
    bktp[it] = bkt + (long)row * 512 + g * 8;
  }

  const int jperm = (c >> 2) * 8 + (c & 3);
  int koff[2][2];
#pragma unroll
  for (int jt = 0; jt < 2; ++jt) {
    int jp = jperm + jt * 4;
#pragma unroll
    for (int kk = 0; kk < 2; ++kk)
      koff[jt][kk] = jp * 128 + (((kk * 4 + g) ^ (jp & 7)) << 4);
  }
  int voff[4];
#pragma unroll
  for (int dt = 0; dt < 4; ++dt) {
    int r = dt * 16 + c;
    voff[dt] = 4096 + r * 64 + ((g ^ (r & 3)) << 4);
  }

  f32x4 oacc[4][4] = {};
  float lp[4] = {0.f, 0.f, 0.f, 0.f};

  int rb = 0, wbuf = 2;
#pragma unroll 1
  for (int kt = 0; kt < 16; ++kt) {
    asm volatile("s_waitcnt vmcnt(1)" ::: "memory");
    __builtin_amdgcn_s_barrier();
    int kn = (kt < 14) ? kt + 2 : 15;   // clamped junk re-stage at tail
    STAGE(kn, wbuf);

    const char* lb = ring + rb * 8192;
    const int jb = kt * 32;

    Frag kf[2][2];
#pragma unroll
    for (int jt = 0; jt < 2; ++jt)
#pragma unroll
      for (int kk = 0; kk < 2; ++kk)
        kf[jt][kk].v = *(const bf16x8*)(lb + koff[jt][kk]);

    uint2 bb[4];
#pragma unroll
    for (int it = 0; it < 4; ++it)
      bb[it] = *(const uint2*)(bktp[it] + jb);

    f32x4 s[2][4];
#pragma unroll
    for (int jt = 0; jt < 2; ++jt)
#pragma unroll
      for (int it = 0; it < 4; ++it) {
        f32x4 z = {0.f, 0.f, 0.f, 0.f};
        z = __builtin_amdgcn_mfma_f32_16x16x32_bf16(kf[jt][0].v, qu[it][0].v, z, 0, 0, 0);
        s[jt][it] = __builtin_amdgcn_mfma_f32_16x16x32_bf16(kf[jt][1].v, qu[it][1].v, z, 0, 0, 0);
      }

    Frag pfr[4];
#pragma unroll
    for (int it = 0; it < 4; ++it) {
      float ps = 0.f;
#pragma unroll
      for (int jt = 0; jt < 2; ++jt) {
        unsigned int bw = jt ? bb[it].y : bb[it].x;
#pragma unroll
        for (int r = 0; r < 4; ++r) {
          int bno = (bw >> (8 * r)) & 255;
          float bias = *(const float*)((const char*)lt_lds + rowb36[it] + (bno << 2));
          float sv = s[jt][it][r] + bias;
          float p;
          asm("v_exp_f32 %0, %1" : "=v"(p) : "v"(sv));
          ps += p;
          pfr[it].hf[jt * 4 + r] = (__bf16)p;
        }
      }
      lp[it] += ps;
    }

    bf16x8 vf[4];
#pragma unroll
    for (int dt = 0; dt < 4; ++dt)
      vf[dt] = *(const bf16x8*)(lb + voff[dt]);

#pragma unroll
    for (int dt = 0; dt < 4; ++dt)
#pragma unroll
      for (int it = 0; it < 4; ++it)
        oacc[dt][it] = __builtin_amdgcn_mfma_f32_16x16x32_bf16(vf[dt], pfr[it].v, oacc[dt][it], 0, 0, 0);

    asm volatile("s_waitcnt lgkmcnt(0)" ::: "memory");
    rb = (rb == 2) ? 0 : rb + 1;
    wbuf = (wbuf == 2) ? 0 : wbuf + 1;
  }
  asm volatile("s_waitcnt vmcnt(0)" ::: "memory");
#undef STAGE

  float li[4];
#pragma unroll
  for (int it = 0; it < 4; ++it) {
    float v = lp[it];
    v += __shfl_xor(v, 16);
    v += __shfl_xor(v, 32);
    li[it] = 1.0f / v;
  }
#pragma unroll
  for (int dt = 0; dt < 4; ++dt)
#pragma unroll
    for (int it = 0; it < 4; ++it) {
      int irow = qbase + it * 16 + c;
      int d0 = dt * 16 + g * 4;
      unsigned int w0 = f2bf(oacc[dt][it][0] * li[it]) | ((unsigned)f2bf(oacc[dt][it][1] * li[it]) << 16);
      unsigned int w1 = f2bf(oacc[dt][it][2] * li[it]) | ((unsigned)f2bf(oacc[dt][it][3] * li[it]) << 16);
      *(uint2*)(ao + ((long)(b * 512 + irow)) * 1024 + h * 64 + d0) = make_uint2(w0, w1);
    }
}

// ---------------------------------------------------------------------------
extern "C" void kernel_launch(void* const* d_in, const int* in_sizes, int n_in,
                              void* d_out, int out_size, void* d_ws, size_t ws_size,
                              hipStream_t stream) {
  const float* x   = (const float*)d_in[0];
  const float* wq  = (const float*)d_in[1];
  const float* wk  = (const float*)d_in[2];
  const float* wv  = (const float*)d_in[3];
  const float* rpe = (const float*)d_in[4];
  const float* pw  = (const float*)d_in[5];
  const float* pb  = (const float*)d_in[6];
  float* out = (float*)d_out;

  char* ws = (char*)d_ws;
  unsigned short* xb  = (unsigned short*)(ws);                 // 8192x1024 bf16 (16 MB)
  unsigned short* wb  = (unsigned short*)(ws + 16777216);      // 4x1024x1024 bf16 (8 MB)
  unsigned short* qhp = (unsigned short*)(ws + 25165824);      // [bh][512][64]
  unsigned short* khp = (unsigned short*)(ws + 41943040);      // [bh][512][64]
  unsigned short* vtp = (unsigned short*)(ws + 58720256);      // [bh][64][512]
  unsigned char*  bkt = (unsigned char*)(ws + 75497472);       // 512x512
  unsigned short* aop = xb;                                    // alias: xb dead after QKV gemm

  k_prep<<<dim3(7168), dim3(256), 0, stream>>>(x, wq, wk, wv, pw, xb, wb, bkt);
  k_gemm8<<<dim3(512), dim3(512), 0, stream>>>(xb, wb, qhp, khp, vtp);
  k_attn<<<dim3(256), dim3(512), 0, stream>>>(qhp, khp, vtp, rpe, bkt, aop);
  k_gemm_proj<<<dim3(256), dim3(512), 0, stream>>>(aop, wb + 3 * 1048576, out, pb);
}

// Round 15
// 139.424 us; speedup vs baseline: 1.2131x; 1.0645x over previous
//
#include <hip/hip_runtime.h>

typedef __attribute__((ext_vector_type(8))) __bf16 bf16x8;
typedef __attribute__((ext_vector_type(4))) float f32x4;

#define DEVI static __device__ __forceinline__

DEVI unsigned short f2bf(float f) {
  unsigned int u = __float_as_uint(f);
  u += 0x7fffu + ((u >> 16) & 1u);
  return (unsigned short)(u >> 16);
}
DEVI float bf2f(unsigned short s) {
  return __uint_as_float(((unsigned int)s) << 16);
}

union Frag {
  bf16x8 v;
  __bf16 hf[8];
  unsigned short h[8];
  unsigned int w[4];
};

typedef __attribute__((address_space(1))) const void gv_t;
typedef __attribute__((address_space(3))) void sv_t;
#define GLOAD_LDS16(gp, lp) __builtin_amdgcn_global_load_lds((gv_t*)(gp), (sv_t*)(lp), 16, 0, 0)

// 0.125 * log2(e)
#define QSCALE 0.18033688011112042f

// ---------------------------------------------------------------------------
// Prep: fp32->bf16 conversion (x slice + 4 weights) AND iRPE bucket table.
// ---------------------------------------------------------------------------
__global__ __launch_bounds__(256) void k_prep(
    const float* __restrict__ x, const float* __restrict__ wq,
    const float* __restrict__ wk, const float* __restrict__ wv,
    const float* __restrict__ pw,
    unsigned short* __restrict__ xb, unsigned short* __restrict__ wb,
    unsigned char* __restrict__ bkt)
{
  int t = blockIdx.x * 256 + threadIdx.x;
  if (t >= 1572864) {  // bucket table
    int q = t - 1572864;               // 0..262143
    int i = q >> 9, j = q & 511;
    int ir = i / 23, ic = i - ir * 23;
    int jr = j / 23, jc = j - jr * 23;
    int dy = ir - jr, dx = ic - jc;
    double dis = rint(sqrt((double)(dy * dy + dx * dx)));
    int v;
    if (dis <= 1.9) {
      v = (int)rint(dis);
    } else {
      double far = rint(1.9 + log(dis / 1.9) * (1.9 / log(8.0)));
      v = (int)fmin(far, 3.8);
    }
    bkt[q] = (unsigned char)v;
    return;
  }
  const float* src;
  unsigned short* dst;
  if (t < 1048576) {
    long e0 = (long)t << 3;
    int m = (int)(e0 >> 10), cc = (int)(e0 & 1023);
    int b = m >> 9, i = m & 511;
    src = x + (((long)(b << 10) + i) << 10) + cc;
    dst = xb + ((long)m << 10) + cc;
  } else {
    long e0 = (long)(t - 1048576) << 3;
    int mat = (int)(e0 >> 20);
    long off = e0 & 1048575;
    const float* s = (mat == 0) ? wq : (mat == 1) ? wk : (mat == 2) ? wv : pw;
    src = s + off;
    dst = wb + e0;
  }
  float4 a = *(const float4*)src;
  float4 b4 = *(const float4*)(src + 4);
  uint4 o;
  o.x = f2bf(a.x)  | ((unsigned)f2bf(a.y)  << 16);
  o.y = f2bf(a.z)  | ((unsigned)f2bf(a.w)  << 16);
  o.z = f2bf(b4.x) | ((unsigned)f2bf(b4.y) << 16);
  o.w = f2bf(b4.z) | ((unsigned)f2bf(b4.w) << 16);
  *(uint4*)dst = o;
}

// ---------------------------------------------------------------------------
// QKV GEMM (R12 ring-dbuf, best measured 59us): 256x192, BK=64, grid 512
// (balanced 2 rounds), 2-half schedule, counted vmcnt(2)/vmcnt(5).
// ---------------------------------------------------------------------------
__global__ __launch_bounds__(512) void k_gemm8(
    const unsigned short* __restrict__ A,
    const unsigned short* __restrict__ Bw,
    unsigned short* __restrict__ qh, unsigned short* __restrict__ kh,
    unsigned short* __restrict__ vt)
{
  __shared__ unsigned short sL[2 * 28672];   // 114688 B

  const int bid = blockIdx.x;                 // 512 = 32 M x 16 N
  const int swz = (bid & 7) * 64 + (bid >> 3);   // bijective XCD swizzle
  const int tileN = swz & 15, tileM = swz >> 4;

  const int t = threadIdx.x;
  const int w = t >> 6, lane = t & 63;
  const int g4 = lane >> 4, c = lane & 15;
  const int wm = w >> 2, wn = w & 3;

  const char* lbase = (const char*)sL;
  const int acb = c * 64 + ((g4 * 16) ^ ((c & 8) ? 32 : 0));
  const int aoffbase = wm * 8192 + acb;
  int boff[3][2];
#pragma unroll
  for (int ni = 0; ni < 3; ++ni) {
    int row = wn * 48 + ni * 16 + c;
    int base = 32768 + (row >> 6) * 8192 + (row & 63) * 128;
    int rx = row & 7;
#pragma unroll
    for (int kk = 0; kk < 2; ++kk)
      boff[ni][kk] = base + (((kk * 4 + g4) ^ rx) << 4);
  }

  const int rowa = w * 16 + (lane >> 2);
  const int cola = ((lane & 3) * 8) ^ (((lane >> 2) & 8) ? 16 : 0);
  const unsigned short* sAp = A + (long)(tileM * 256 + rowa) * 1024 + cola;
  char* ldsta = (char*)sL + t * 16;
  const int rowbb = t >> 3;
  const int colbb = ((t & 7) ^ ((t >> 3) & 7)) * 8;
  const unsigned short* sBp = Bw + (long)(tileN * 192 + rowbb) * 1024 + colbb;
  char* ldstb = (char*)sL + 32768 + t * 16;

#define STGA(rh, kh, kn, ob) \
  GLOAD_LDS16(sAp + (long)(kn) * 64 + (rh) * 131072 + (kh) * 32, \
              ldsta + (ob) + (kh) * 16384 + (rh) * 8192)
#define STGB(gg, kn, ob) \
  GLOAD_LDS16(sBp + (long)(kn) * 64 + (gg) * 65536, \
              ldstb + (ob) + (gg) * 8192)

  f32x4 acc[8][3] = {};

  STGA(0, 0, 0, 0); STGA(1, 0, 0, 0);
  STGB(0, 0, 0); STGB(1, 0, 0); STGB(2, 0, 0);
  STGA(0, 1, 0, 0); STGA(1, 1, 0, 0);

#pragma unroll 1
  for (int kt = 0; kt < 16; ++kt) {
    const int cb = (kt & 1) ? 57344 : 0;
    const int ob = cb ^ 57344;
    const int kn = (kt < 15) ? kt + 1 : 15;

    // ---- HALF 0 (kk = 0) ----
    {
      asm volatile("s_waitcnt vmcnt(2)" ::: "memory");
      __builtin_amdgcn_s_barrier();
      bf16x8 aa[4], bbf[3];
#pragma unroll
      for (int q = 0; q < 4; ++q)
        aa[q] = *(const bf16x8*)(lbase + cb + aoffbase + q * 1024);
#pragma unroll
      for (int ni = 0; ni < 3; ++ni)
        bbf[ni] = *(const bf16x8*)(lbase + cb + boff[ni][0]);
      STGA(0, 0, kn, ob); STGA(1, 0, kn, ob); STGB(0, kn, ob);
      __builtin_amdgcn_s_setprio(1);
#pragma unroll
      for (int mi = 0; mi < 4; ++mi)
#pragma unroll
        for (int ni = 0; ni < 3; ++ni)
          acc[mi][ni] = __builtin_amdgcn_mfma_f32_16x16x32_bf16(aa[mi], bbf[ni], acc[mi][ni], 0, 0, 0);
      __builtin_amdgcn_s_setprio(0);
      bf16x8 a2[4];
#pragma unroll
      for (int q = 0; q < 4; ++q)
        a2[q] = *(const bf16x8*)(lbase + cb + aoffbase + (4 + q) * 1024);
      STGB(1, kn, ob); STGB(2, kn, ob);
      __builtin_amdgcn_s_setprio(1);
#pragma unroll
      for (int mi = 0; mi < 4; ++mi)
#pragma unroll
        for (int ni = 0; ni < 3; ++ni)
          acc[4 + mi][ni] = __builtin_amdgcn_mfma_f32_16x16x32_bf16(a2[mi], bbf[ni], acc[4 + mi][ni], 0, 0, 0);
      __builtin_amdgcn_s_setprio(0);
    }
    // ---- HALF 1 (kk = 1) ----
    {
      asm volatile("s_waitcnt vmcnt(5)" ::: "memory");
      __builtin_amdgcn_s_barrier();
      bf16x8 aa[4], bbf[3];
#pragma unroll
      for (int q = 0; q < 4; ++q)
        aa[q] = *(const bf16x8*)(lbase + cb + 16384 + aoffbase + q * 1024);
#pragma unroll
      for (int ni = 0; ni < 3; ++ni)
        bbf[ni] = *(const bf16x8*)(lbase + cb + boff[ni][1]);
      STGA(0, 1, kn, ob);
      __builtin_amdgcn_s_setprio(1);
#pragma unroll
      for (int mi = 0; mi < 4; ++mi)
#pragma unroll
        for (int ni = 0; ni < 3; ++ni)
          acc[mi][ni] = __builtin_amdgcn_mfma_f32_16x16x32_bf16(aa[mi], bbf[ni], acc[mi][ni], 0, 0, 0);
      __builtin_amdgcn_s_setprio(0);
      bf16x8 a2[4];
#pragma unroll
      for (int q = 0; q < 4; ++q)
        a2[q] = *(const bf16x8*)(lbase + cb + 16384 + aoffbase + (4 + q) * 1024);
      STGA(1, 1, kn, ob);
      __builtin_amdgcn_s_setprio(1);
#pragma unroll
      for (int mi = 0; mi < 4; ++mi)
#pragma unroll
        for (int ni = 0; ni < 3; ++ni)
          acc[4 + mi][ni] = __builtin_amdgcn_mfma_f32_16x16x32_bf16(a2[mi], bbf[ni], acc[4 + mi][ni], 0, 0, 0);
      __builtin_amdgcn_s_setprio(0);
    }
  }
  asm volatile("s_waitcnt vmcnt(0)" ::: "memory");
#undef STGA
#undef STGB

  const int m0 = tileM * 256 + wm * 128;
  const int n0 = tileN * 192 + wn * 48;
#pragma unroll
  for (int mi = 0; mi < 8; ++mi) {
    int mrow = m0 + mi * 16 + g4 * 4;
    int b = mrow >> 9, i = mrow & 511;
#pragma unroll
    for (int ni = 0; ni < 3; ++ni) {
      int n = n0 + ni * 16 + c;
      int mat = n >> 10;
      int cc = n & 1023;
      int h = cc >> 6, d = cc & 63;
      long bh = (long)(b * 16 + h);
      if (mat == 2) {
        unsigned int w0 = f2bf(acc[mi][ni][0]) | ((unsigned)f2bf(acc[mi][ni][1]) << 16);
        unsigned int w1 = f2bf(acc[mi][ni][2]) | ((unsigned)f2bf(acc[mi][ni][3]) << 16);
        *(uint2*)(vt + (bh * 64 + d) * 512 + i) = make_uint2(w0, w1);
      } else {
        float sc = (mat == 0) ? QSCALE : 1.0f;   // prescale Q for exp2 softmax
        unsigned short* dst = (mat == 0 ? qh : kh) + (bh * 512 + i) * 64 + d;
#pragma unroll
        for (int r = 0; r < 4; ++r)
          dst[(long)r * 64] = f2bf(acc[mi][ni][r] * sc);
      }
    }
  }
}

// ---------------------------------------------------------------------------
// Proj GEMM (ring-3, proven): BM=256, BN=128, BK=32, 512 thr, fp32 out + bias.
// ---------------------------------------------------------------------------
__global__ __launch_bounds__(512) void k_gemm_proj(
    const unsigned short* __restrict__ A,
    const unsigned short* __restrict__ Bw,
    float* __restrict__ out, const float* __restrict__ bias)
{
  __shared__ unsigned short sL[3 * 12288];   // 73728 B

  const int bid = blockIdx.x;
  const int swz = (bid & 7) * 32 + (bid >> 3);     // 256 blocks
  const int tileN = swz % 8, tileM = swz / 8;

  const int tid = threadIdx.x;
  const int w = tid >> 6, lane = tid & 63;
  const int g = lane >> 4, c = lane & 15;
  const int wm = w >> 1, wn = w & 1;

  const int sk = (g * 8) ^ ((c & 8) ? 16 : 0);
  int offA[4], offB[4];
#pragma unroll
  for (int i = 0; i < 4; ++i) {
    offA[i] = (wm * 4 + i) * 512 + c * 32 + sk;
    offB[i] = 8192 + (wn * 4 + i) * 512 + c * 32 + sk;
  }

  const int colb = ((lane & 3) * 8) ^ ((lane >= 32) ? 16 : 0);
  const unsigned short* gA0 = A  + ((long)(tileM * 256 + w * 32 + (lane >> 2))) * 1024 + colb;
  const unsigned short* gA1 = gA0 + 16 * 1024;
  const unsigned short* gB0 = Bw + ((long)(tileN * 128 + w * 16 + (lane >> 2))) * 1024 + colb;

#define STAGE(ktile, buf) do {                                             \
    const long ko_ = (long)(ktile) * 32;                                   \
    char* base_ = (char*)sL + (buf) * 24576;                               \
    GLOAD_LDS16(gA0 + ko_, base_ + (w * 2) * 1024 + lane * 16);            \
    GLOAD_LDS16(gA1 + ko_, base_ + (w * 2 + 1) * 1024 + lane * 16);        \
    GLOAD_LDS16(gB0 + ko_, base_ + 16384 + w * 1024 + lane * 16);          \
  } while (0)

  f32x4 acc[4][4] = {};

  STAGE(0, 0);
  STAGE(1, 1);

  int rb = 0, wbuf = 2;
  for (int t = 0; t < 32; ++t) {
    asm volatile("s_waitcnt vmcnt(3)" ::: "memory");
    __builtin_amdgcn_s_barrier();
    int kt = t + 2; if (kt > 31) kt = 31;
    STAGE(kt, wbuf);

    const unsigned short* lb = sL + rb * 12288;
    bf16x8 af[4], bf[4];
#pragma unroll
    for (int i = 0; i < 4; ++i) af[i] = *(const bf16x8*)(lb + offA[i]);
#pragma unroll
    for (int i = 0; i < 4; ++i) bf[i] = *(const bf16x8*)(lb + offB[i]);

    __builtin_amdgcn_s_setprio(1);
#pragma unroll
    for (int mi = 0; mi < 4; ++mi)
#pragma unroll
      for (int ni = 0; ni < 4; ++ni)
        acc[mi][ni] = __builtin_amdgcn_mfma_f32_16x16x32_bf16(af[mi], bf[ni], acc[mi][ni], 0, 0, 0);
    __builtin_amdgcn_s_setprio(0);
    asm volatile("s_waitcnt lgkmcnt(0)" ::: "memory");

    rb = (rb == 2) ? 0 : rb + 1;
    wbuf = (wbuf == 2) ? 0 : wbuf + 1;
  }
  asm volatile("s_waitcnt vmcnt(0)" ::: "memory");
#undef STAGE

  const int m0 = tileM * 256 + wm * 64;
  const int n0 = tileN * 128 + wn * 64;
#pragma unroll
  for (int mi = 0; mi < 4; ++mi) {
    int mrow = m0 + mi * 16 + g * 4;
#pragma unroll
    for (int ni = 0; ni < 4; ++ni) {
      int n = n0 + ni * 16 + c;
      float bv = bias[n];
#pragma unroll
      for (int r = 0; r < 4; ++r)
        out[(long)(mrow + r) * 1024 + n] = acc[mi][ni][r] + bv;
    }
  }
}

// ---------------------------------------------------------------------------
// Fused attention v15: FULL K/V LDS staging. 256 blocks x 512 thr, it=4,
// exp2 no-max softmax. All 16 K/V tiles staged up-front (16 global_load_lds
// per thread, pre-swizzled layout), ONE vmcnt(0) + ONE barrier, then a
// 16-tile main loop with ZERO barriers/waitcnts — LDS is read-only, so the
// compiler can pipeline softmax(t) with QK(t+1) freely (R12 paid 16 barrier
// round-trips). LDS: K 64KB + V 64KB + lt 18KB = 146.4KB (<=160).
// Unified-reg: 104 arch + 64 acc = 168 -> 2 waves/SIMD hard cap at it=4.
// ---------------------------------------------------------------------------
__global__ __launch_bounds__(512) void k_attn(
    const unsigned short* __restrict__ qh, const unsigned short* __restrict__ kh,
    const unsigned short* __restrict__ vt, const float* __restrict__ rpe,
    const unsigned char* __restrict__ bkt, unsigned short* __restrict__ ao)
{
  __shared__ char ring[131072];        // K tiles [16][32][64] @0, V tiles [16][64][32] @65536
  __shared__ float lt_lds[512 * 9];
  const int head = blockIdx.x;
  const int b = head >> 4, h = head & 15;
  const int t = threadIdx.x;
  const int w = t >> 6, lane = t & 63;
  const int g = lane >> 4, c = lane & 15;
  const int qbase = w * 64;
  const unsigned short* Q = qh + (long)head * 512 * 64;
  const unsigned short* K = kh + (long)head * 512 * 64;
  const unsigned short* V = vt + (long)head * 64 * 512;

  // stage sources (pre-swizzled), dest tile-indexed:
  // threads 0-255: K row t>>3 (j in tile), slot t&7, src d-chunk (t&7)^(row&7)
  // threads 256-511: u=t-256: V row u>>2 (d), slot u&3, src j-chunk (u&3)^(row&3)
  const unsigned short* sgp;
  char* sld;
  int sjstep;
  if (t < 256) {
    int row = t >> 3;
    int chunk = (t & 7) ^ (row & 7);
    sgp = K + (long)row * 64 + chunk * 8;
    sld = ring + t * 16;
    sjstep = 64;
  } else {
    int u = t - 256;
    int row = u >> 2;
    int chunk = (u & 3) ^ (row & 3);
    sgp = V + (long)row * 512 + chunk * 8;
    sld = ring + 65536 + u * 16;
    sjstep = 1;
  }

  // --- load Q fragments (persist; prescaled by QSCALE) ---
  Frag qu[4][2];
#pragma unroll
  for (int it = 0; it < 4; ++it)
#pragma unroll
    for (int kk = 0; kk < 2; ++kk)
      qu[it][kk].v = *(const bf16x8*)(Q + (qbase + it * 16 + c) * 64 + kk * 32 + g * 8);

  // --- issue ALL 16 tile stages (K 4KB + V 4KB per tile, 1 op/thread/tile) ---
#pragma unroll
  for (int kt = 0; kt < 16; ++kt)
    GLOAD_LDS16(sgp + (long)kt * 32 * sjstep, sld + kt * 4096);

  // --- lt[i][n] = sum_d q'[i][d]*rpe[d][n]; stored x8 (hides stage flight) ---
  float lt[4][7] = {};
#pragma unroll
  for (int kk = 0; kk < 2; ++kk)
#pragma unroll
    for (int tt = 0; tt < 8; ++tt) {
      int d = kk * 32 + g * 8 + tt;
      const float* rr = rpe + d * 7;
      float r0 = rr[0], r1 = rr[1], r2 = rr[2], r3 = rr[3], r4 = rr[4], r5 = rr[5], r6 = rr[6];
#pragma unroll
      for (int it = 0; it < 4; ++it) {
        float qv = bf2f(qu[it][kk].h[tt]);
        lt[it][0] += qv * r0; lt[it][1] += qv * r1; lt[it][2] += qv * r2;
        lt[it][3] += qv * r3; lt[it][4] += qv * r4; lt[it][5] += qv * r5;
        lt[it][6] += qv * r6;
      }
    }
#pragma unroll
  for (int it = 0; it < 4; ++it)
#pragma unroll
    for (int n = 0; n < 7; ++n) {
      float v = lt[it][n];
      v += __shfl_xor(v, 16);
      v += __shfl_xor(v, 32);
      if (g == 0) lt_lds[(qbase + it * 16 + c) * 9 + n] = v * 8.0f;
    }
  // wave-local lt write->read: covered by the block barrier below

  int rowb36[4];
  const unsigned char* bktp[4];
#pragma unroll
  for (int it = 0; it < 4; ++it) {
    int row = qbase + it * 16 + c;
    rowb36[it] = row * 36;
    bktp[it] = bkt + (long)row * 512 + g * 8;
  }

  // LDS read offsets (within a K tile / V tile)
  const int jperm = (c >> 2) * 8 + (c & 3);
  int koff[2][2];   // [jt][kk]
#pragma unroll
  for (int jt = 0; jt < 2; ++jt) {
    int jp = jperm + jt * 4;
#pragma unroll
    for (int kk = 0; kk < 2; ++kk)
      koff[jt][kk] = jp * 128 + (((kk * 4 + g) ^ (jp & 7)) << 4);
  }
  int voff[4];      // [dt]
#pragma unroll
  for (int dt = 0; dt < 4; ++dt) {
    int r = dt * 16 + c;
    voff[dt] = r * 64 + ((g ^ (r & 3)) << 4);
  }

  f32x4 oacc[4][4] = {};          // [dt][it]
  float lp[4] = {0.f, 0.f, 0.f, 0.f};

  // all staging landed; LDS read-only from here: single sync for whole kernel
  asm volatile("s_waitcnt vmcnt(0)" ::: "memory");
  __builtin_amdgcn_s_barrier();

#pragma unroll 1
  for (int kt = 0; kt < 16; ++kt) {
    const char* lb = ring + kt * 4096;            // K tile
    const char* lv = ring + 65536 + kt * 4096;    // V tile
    const int jb = kt * 32;

    Frag kf[2][2];
#pragma unroll
    for (int jt = 0; jt < 2; ++jt)
#pragma unroll
      for (int kk = 0; kk < 2; ++kk)
        kf[jt][kk].v = *(const bf16x8*)(lb + koff[jt][kk]);

    uint2 bb[4];
#pragma unroll
    for (int it = 0; it < 4; ++it)
      bb[it] = *(const uint2*)(bktp[it] + jb);

    f32x4 s[2][4];
#pragma unroll
    for (int jt = 0; jt < 2; ++jt)
#pragma unroll
      for (int it = 0; it < 4; ++it) {
        f32x4 z = {0.f, 0.f, 0.f, 0.f};
        z = __builtin_amdgcn_mfma_f32_16x16x32_bf16(kf[jt][0].v, qu[it][0].v, z, 0, 0, 0);
        s[jt][it] = __builtin_amdgcn_mfma_f32_16x16x32_bf16(kf[jt][1].v, qu[it][1].v, z, 0, 0, 0);
      }

    Frag pfr[4];
#pragma unroll
    for (int it = 0; it < 4; ++it) {
      float ps = 0.f;
#pragma unroll
      for (int jt = 0; jt < 2; ++jt) {
        unsigned int bw = jt ? bb[it].y : bb[it].x;
#pragma unroll
        for (int r = 0; r < 4; ++r) {
          int bno = (bw >> (8 * r)) & 255;
          float bias = *(const float*)((const char*)lt_lds + rowb36[it] + (bno << 2));
          float sv = s[jt][it][r] + bias;
          float p;
          asm("v_exp_f32 %0, %1" : "=v"(p) : "v"(sv));
          ps += p;
          pfr[it].hf[jt * 4 + r] = (__bf16)p;
        }
      }
      lp[it] += ps;
    }

    bf16x8 vf[4];
#pragma unroll
    for (int dt = 0; dt < 4; ++dt)
      vf[dt] = *(const bf16x8*)(lv + voff[dt]);

#pragma unroll
    for (int dt = 0; dt < 4; ++dt)
#pragma unroll
      for (int it = 0; it < 4; ++it)
        oacc[dt][it] = __builtin_amdgcn_mfma_f32_16x16x32_bf16(vf[dt], pfr[it].v, oacc[dt][it], 0, 0, 0);
  }

  float li[4];
#pragma unroll
  for (int it = 0; it < 4; ++it) {
    float v = lp[it];
    v += __shfl_xor(v, 16);
    v += __shfl_xor(v, 32);
    li[it] = 1.0f / v;
  }
#pragma unroll
  for (int dt = 0; dt < 4; ++dt)
#pragma unroll
    for (int it = 0; it < 4; ++it) {
      int irow = qbase + it * 16 + c;
      int d0 = dt * 16 + g * 4;
      unsigned int w0 = f2bf(oacc[dt][it][0] * li[it]) | ((unsigned)f2bf(oacc[dt][it][1] * li[it]) << 16);
      unsigned int w1 = f2bf(oacc[dt][it][2] * li[it]) | ((unsigned)f2bf(oacc[dt][it][3] * li[it]) << 16);
      *(uint2*)(ao + ((long)(b * 512 + irow)) * 1024 + h * 64 + d0) = make_uint2(w0, w1);
    }
}

// ---------------------------------------------------------------------------
extern "C" void kernel_launch(void* const* d_in, const int* in_sizes, int n_in,
                              void* d_out, int out_size, void* d_ws, size_t ws_size,
                              hipStream_t stream) {
  const float* x   = (const float*)d_in[0];
  const float* wq  = (const float*)d_in[1];
  const float* wk  = (const float*)d_in[2];
  const float* wv  = (const float*)d_in[3];
  const float* rpe = (const float*)d_in[4];
  const float* pw  = (const float*)d_in[5];
  const float* pb  = (const float*)d_in[6];
  float* out = (float*)d_out;

  char* ws = (char*)d_ws;
  unsigned short* xb  = (unsigned short*)(ws);                 // 8192x1024 bf16 (16 MB)
  unsigned short* wb  = (unsigned short*)(ws + 16777216);      // 4x1024x1024 bf16 (8 MB)
  unsigned short* qhp = (unsigned short*)(ws + 25165824);      // [bh][512][64]
  unsigned short* khp = (unsigned short*)(ws + 41943040);      // [bh][512][64]
  unsigned short* vtp = (unsigned short*)(ws + 58720256);      // [bh][64][512]
  unsigned char*  bkt = (unsigned char*)(ws + 75497472);       // 512x512
  unsigned short* aop = xb;                                    // alias: xb dead after QKV gemm

  k_prep<<<dim3(7168), dim3(256), 0, stream>>>(x, wq, wk, wv, pw, xb, wb, bkt);
  k_gemm8<<<dim3(512), dim3(512), 0, stream>>>(xb, wb, qhp, khp, vtp);
  k_attn<<<dim3(256), dim3(512), 0, stream>>>(qhp, khp, vtp, rpe, bkt, aop);
  k_gemm_proj<<<dim3(256), dim3(512), 0, stream>>>(aop, wb + 3 * 1048576, out, pb);
}